// Round 11
// baseline (1051.024 us; speedup 1.0000x reference)
//
#include <hip/hip_runtime.h>

#define NB 64
#define NN 128
#define ND 2048

// ---------------------------------------------------------------------------
// Kernel A: cost[b][i][j] = sqrt(max(||x_i||^2 + ||y_j||^2 - 2 x_i.y_j, 0))
// (round-9 version — 256 blocks, 32-row x 128-col tiles)
// ---------------------------------------------------------------------------
__global__ __launch_bounds__(256) void cost_kernel(const float* __restrict__ X,
                                                   const float* __restrict__ Y,
                                                   float* __restrict__ cost) {
  const int b  = blockIdx.x >> 2;
  const int rt = blockIdx.x & 3;
  const int rbase = rt * 32;
  __shared__ float Xs[32][33];    // [k][row], padded
  __shared__ float Ys[32][129];   // [k][col], padded
  __shared__ float xsq_s[32];
  __shared__ float ysq_s[128];
  const int tid = threadIdx.x;
  const int tr = tid >> 5;        // 0..7
  const int tc = tid & 31;        // 0..31
  float acc[4][4] = {{0.f,0.f,0.f,0.f},{0.f,0.f,0.f,0.f},
                     {0.f,0.f,0.f,0.f},{0.f,0.f,0.f,0.f}};
  float xsq[4] = {0.f,0.f,0.f,0.f};
  float ysq[4] = {0.f,0.f,0.f,0.f};
  const float* Xb = X + ((size_t)(b * NN + rbase)) * ND;
  const float* Yb = Y + ((size_t)(b * NN)) * ND;
  const int lrow = tid >> 3;          // 0..31
  const int lkk  = (tid & 7) << 2;    // 0,4,..,28

  for (int kb = 0; kb < ND; kb += 32) {
    __syncthreads();
    {
      float4 xv = *(const float4*)(Xb + (size_t)lrow * ND + kb + lkk);
      Xs[lkk + 0][lrow] = xv.x; Xs[lkk + 1][lrow] = xv.y;
      Xs[lkk + 2][lrow] = xv.z; Xs[lkk + 3][lrow] = xv.w;
    }
#pragma unroll
    for (int l = 0; l < 4; ++l) {
      int idx = tid + 256 * l;
      int col = idx >> 3;
      int kk  = (idx & 7) << 2;
      float4 yv = *(const float4*)(Yb + (size_t)col * ND + kb + kk);
      Ys[kk + 0][col] = yv.x; Ys[kk + 1][col] = yv.y;
      Ys[kk + 2][col] = yv.z; Ys[kk + 3][col] = yv.w;
    }
    __syncthreads();
#pragma unroll 4
    for (int kk = 0; kk < 32; ++kk) {
      float xv[4], yv[4];
#pragma unroll
      for (int ii = 0; ii < 4; ++ii) xv[ii] = Xs[kk][4 * tr + ii];
#pragma unroll
      for (int jj = 0; jj < 4; ++jj) yv[jj] = Ys[kk][tc + 32 * jj];
#pragma unroll
      for (int ii = 0; ii < 4; ++ii) xsq[ii] += xv[ii] * xv[ii];
#pragma unroll
      for (int jj = 0; jj < 4; ++jj) ysq[jj] += yv[jj] * yv[jj];
#pragma unroll
      for (int ii = 0; ii < 4; ++ii)
#pragma unroll
        for (int jj = 0; jj < 4; ++jj)
          acc[ii][jj] += xv[ii] * yv[jj];
    }
  }
  if (tc == 0) {
#pragma unroll
    for (int ii = 0; ii < 4; ++ii) xsq_s[4 * tr + ii] = xsq[ii];
  }
  if (tr == 0) {
#pragma unroll
    for (int jj = 0; jj < 4; ++jj) ysq_s[tc + 32 * jj] = ysq[jj];
  }
  __syncthreads();
#pragma unroll
  for (int ii = 0; ii < 4; ++ii) {
    int r = rbase + 4 * tr + ii;
    float xs = xsq_s[4 * tr + ii];
#pragma unroll
    for (int jj = 0; jj < 4; ++jj) {
      int c = tc + 32 * jj;
      float d2 = xs + ysq_s[c] - 2.0f * acc[ii][jj];
      cost[((size_t)(b * NN + r)) * NN + c] = sqrtf(fmaxf(d2, 0.0f));
    }
  }
}

// ---------------------------------------------------------------------------
// Cross-lane helpers (DPP-only; no ds_bpermute anywhere). x2 variants
// interleave two independent reductions to hide VALU dep-latency.
// ---------------------------------------------------------------------------
__device__ __forceinline__ unsigned umin2(unsigned a, unsigned b) { return a < b ? a : b; }
__device__ __forceinline__ unsigned umax2(unsigned a, unsigned b) { return a > b ? a : b; }

template <int CTRL, int RMASK>
__device__ __forceinline__ unsigned dppmin1(unsigned x) {
  unsigned t = (unsigned)__builtin_amdgcn_update_dpp((int)x, (int)x, CTRL, RMASK, 0xF, false);
  return umin2(x, t);
}

// fused wave-min of two independent keys; returns broadcast minima in-place
__device__ __forceinline__ void wave_min_u32x2(unsigned& a, unsigned& b) {
  a = dppmin1<0x111, 0xF>(a); b = dppmin1<0x111, 0xF>(b);
  a = dppmin1<0x112, 0xF>(a); b = dppmin1<0x112, 0xF>(b);
  a = dppmin1<0x114, 0xF>(a); b = dppmin1<0x114, 0xF>(b);
  a = dppmin1<0x118, 0xF>(a); b = dppmin1<0x118, 0xF>(b);
  a = dppmin1<0x142, 0xA>(a); b = dppmin1<0x142, 0xA>(b);
  a = dppmin1<0x143, 0xC>(a); b = dppmin1<0x143, 0xC>(b);
  a = (unsigned)__builtin_amdgcn_readlane((int)a, 63);
  b = (unsigned)__builtin_amdgcn_readlane((int)b, 63);
}

// dual (min, 2nd-min) step; requires a <= b per lane on entry. Valid for the
// non-idempotent 2nd-min combine: lane-63 path merges disjoint windows.
template <int CTRL, int RMASK>
__device__ __forceinline__ void min2_step(unsigned& a, unsigned& b) {
  unsigned ap = (unsigned)__builtin_amdgcn_update_dpp((int)a, (int)a, CTRL, RMASK, 0xF, false);
  unsigned bp = (unsigned)__builtin_amdgcn_update_dpp((int)b, (int)b, CTRL, RMASK, 0xF, false);
  unsigned hi = umax2(a, ap);
  a = umin2(a, ap);
  b = umin2(umin2(b, bp), hi);
}

// fused dual-min for two independent batches
__device__ __forceinline__ void wave_min2_u32x2(unsigned aA, unsigned bA,
                                                unsigned aB, unsigned bB,
                                                unsigned& m1A, unsigned& m2A,
                                                unsigned& m1B, unsigned& m2B) {
  min2_step<0x111, 0xF>(aA, bA); min2_step<0x111, 0xF>(aB, bB);
  min2_step<0x112, 0xF>(aA, bA); min2_step<0x112, 0xF>(aB, bB);
  min2_step<0x114, 0xF>(aA, bA); min2_step<0x114, 0xF>(aB, bB);
  min2_step<0x118, 0xF>(aA, bA); min2_step<0x118, 0xF>(aB, bB);
  min2_step<0x142, 0xA>(aA, bA); min2_step<0x142, 0xA>(aB, bB);
  min2_step<0x143, 0xC>(aA, bA); min2_step<0x143, 0xC>(aB, bB);
  m1A = (unsigned)__builtin_amdgcn_readlane((int)aA, 63);
  m2A = (unsigned)__builtin_amdgcn_readlane((int)bA, 63);
  m1B = (unsigned)__builtin_amdgcn_readlane((int)aB, 63);
  m2B = (unsigned)__builtin_amdgcn_readlane((int)bB, 63);
}

__device__ __forceinline__ double readlane_f64(double d, int lane) {
  int lo = __builtin_amdgcn_readlane(__double2loint(d), lane);
  int hi = __builtin_amdgcn_readlane(__double2hiint(d), lane);
  return __hiloint2double(hi, lo);
}

// ---------------------------------------------------------------------------
// Kernel B: JV / Hungarian, TWO batches per wave (A = 2*pb, B = 2*pb+1).
// Each batch's math is identical to the validated single-batch solver
// (column reduction + greedy + transfer + ARR + register Dijkstra, exact f64
// state, f32 monotone keys for argmin). Phases are fused into straight-line
// code so batch B's compute hides batch A's LDS/readlane latency.
// State writes guarded per batch; all wave control flow uniform; all loops
// hard-capped (hang-guard).
// ---------------------------------------------------------------------------
__global__ __launch_bounds__(64) void hungarian_kernel(const float* __restrict__ cost,
                                                       int* __restrict__ cols) {
  const int pb = blockIdx.x;          // 0..31
  const int lane = threadIdx.x;
  const int bA = 2 * pb, bB = 2 * pb + 1;
  __shared__ float cstA[NN * NN];     // 64 KB
  __shared__ float cstB[NN * NN];     // 64 KB
  __shared__ int colrowA[NN], colrowB[NN];
  __shared__ int rwinA[NN], rwinB[NN];
  __shared__ double u_rowA[NN + 1], u_rowB[NN + 1];
  __shared__ int queueA[4 * NN + 8], queueB[4 * NN + 8];
  __shared__ int qcntA[1], qcntB[1];

  // ---- load both cost matrices (interleaved float4 streams) ----
  {
    const float4* sA = (const float4*)(cost + (size_t)bA * NN * NN);
    const float4* sB = (const float4*)(cost + (size_t)bB * NN * NN);
    float4* dA = (float4*)cstA;
    float4* dB = (float4*)cstB;
    for (int t = lane; t < NN * NN / 4; t += 64) { dA[t] = sA[t]; dB[t] = sB[t]; }
  }
  for (int t = lane; t <= NN; t += 64) { u_rowA[t] = 0.0; u_rowB[t] = 0.0; }
  __syncthreads();

  // ---- column reduction (fused A/B: 4 independent min chains) ----
  float cminA[2], cminB[2]; int cargrA[2], cargrB[2];
  {
    float mnA0 = cstA[lane], mnA1 = cstA[lane + 64];
    float mnB0 = cstB[lane], mnB1 = cstB[lane + 64];
    int arA0 = 0, arA1 = 0, arB0 = 0, arB1 = 0;
#pragma unroll 4
    for (int r = 1; r < NN; ++r) {
      float a0 = cstA[r * NN + lane], a1 = cstA[r * NN + lane + 64];
      float b0 = cstB[r * NN + lane], b1 = cstB[r * NN + lane + 64];
      if (a0 < mnA0) { mnA0 = a0; arA0 = r; }
      if (a1 < mnA1) { mnA1 = a1; arA1 = r; }
      if (b0 < mnB0) { mnB0 = b0; arB0 = r; }
      if (b1 < mnB1) { mnB1 = b1; arB1 = r; }
    }
    cminA[0] = mnA0; cminA[1] = mnA1; cargrA[0] = arA0; cargrA[1] = arA1;
    cminB[0] = mnB0; cminB[1] = mnB1; cargrB[0] = arB0; cargrB[1] = arB1;
    colrowA[lane] = arA0; colrowA[lane + 64] = arA1;
    colrowB[lane] = arB0; colrowB[lane + 64] = arB1;
  }
  __syncthreads();

  // ---- greedy claim: row r -> smallest col j with colrow[j]==r ----
  int rowwinA[2] = {-1, -1}, rowwinB[2] = {-1, -1};
  for (int j = 0; j < NN; ++j) {
    const int rA = colrowA[j], rB = colrowB[j];   // uniform reads
    if (rA == lane      && rowwinA[0] < 0) rowwinA[0] = j;
    if (rA == lane + 64 && rowwinA[1] < 0) rowwinA[1] = j;
    if (rB == lane      && rowwinB[0] < 0) rowwinB[0] = j;
    if (rB == lane + 64 && rowwinB[1] < 0) rowwinB[1] = j;
  }
  rwinA[lane] = rowwinA[0]; rwinA[lane + 64] = rowwinA[1];
  rwinB[lane] = rowwinB[0]; rwinB[lane + 64] = rowwinB[1];
  const unsigned long long maskA0 = __ballot(rowwinA[0] >= 0);
  const unsigned long long maskA1 = __ballot(rowwinA[1] >= 0);
  const unsigned long long maskB0 = __ballot(rowwinB[0] >= 0);
  const unsigned long long maskB1 = __ballot(rowwinB[1] >= 0);
  __syncthreads();

  // ---- per-column state (registers) ----
  int    pA[2], pB[2];
  double puA[2], puB[2], vA[2], vB[2];
#pragma unroll
  for (int k2 = 0; k2 < 2; ++k2) {
    const int j = lane + 64 * k2;
    const int rA = cargrA[k2], rB = cargrB[k2];
    pA[k2] = (rwinA[rA] == j) ? (rA + 1) : 0;
    pB[k2] = (rwinB[rB] == j) ? (rB + 1) : 0;
    puA[k2] = 0.0; puB[k2] = 0.0;
    vA[k2] = (double)cminA[k2];
    vB[k2] = (double)cminB[k2];
  }

  // ---- reduction transfer (fused) ----
  for (int i = 1; i <= NN; ++i) {
    const bool mA = (i - 1) < 64 ? ((maskA0 >> (i - 1)) & 1ull) : ((maskA1 >> (i - 65)) & 1ull);
    const bool mB = (i - 1) < 64 ? ((maskB0 >> (i - 1)) & 1ull) : ((maskB1 >> (i - 65)) & 1ull);
    if (!mA && !mB) continue;
    const int j1A = mA ? rwinA[i - 1] : 0;
    const int j1B = mB ? rwinB[i - 1] : 0;
    const float a0 = cstA[(i - 1) * NN + lane], a1 = cstA[(i - 1) * NN + lane + 64];
    const float b0 = cstB[(i - 1) * NN + lane], b1 = cstB[(i - 1) * NN + lane + 64];
    double dA0 = (double)a0 - vA[0], dA1 = (double)a1 - vA[1];
    double dB0 = (double)b0 - vB[0], dB1 = (double)b1 - vB[1];
    if (mA && lane == (j1A & 63)) { if (j1A >> 6) dA1 = 1e300; else dA0 = 1e300; }
    if (mB && lane == (j1B & 63)) { if (j1B >> 6) dB1 = 1e300; else dB0 = 1e300; }
    const double dmnA = fmin(dA0, dA1);
    const double dmnB = fmin(dB0, dB1);
    const unsigned kA = __float_as_uint((float)dmnA);
    const unsigned kB = __float_as_uint((float)dmnB);
    unsigned rA = kA, rB = kB;
    wave_min_u32x2(rA, rB);
    const int wlA = (int)__ffsll(__ballot(kA == rA)) - 1;
    const int wlB = (int)__ffsll(__ballot(kB == rB)) - 1;
    const double muA = readlane_f64(dmnA, wlA);
    const double muB = readlane_f64(dmnB, wlB);
    if (mA && lane == (j1A & 63)) {
      if (j1A >> 6) { vA[1] -= muA; puA[1] = muA; } else { vA[0] -= muA; puA[0] = muA; }
    }
    if (mB && lane == (j1B & 63)) {
      if (j1B >> 6) { vB[1] -= muB; puB[1] = muB; } else { vB[0] -= muB; puB[0] = muB; }
    }
  }

  // ---- build ARR queues (lane 0 -> A, lane 1 -> B; same loop shape) ----
  if (lane < 2) {
    int* q = lane ? queueB : queueA;
    const unsigned long long m0 = lane ? maskB0 : maskA0;
    const unsigned long long m1 = lane ? maskB1 : maskA1;
    int t = 0;
    for (int r = 1; r <= NN; ++r) {
      const bool m = (r - 1) < 64 ? ((m0 >> (r - 1)) & 1ull) : ((m1 >> (r - 65)) & 1ull);
      if (!m) q[t++] = r;
    }
    if (lane) qcntB[0] = t; else qcntA[0] = t;
  }
  __syncthreads();

  // ---- augmenting row reduction (fused A/B, software-pipelined) ----
  {
    int headA = 0, tailA = qcntA[0], popsA = 0;
    int headB = 0, tailB = qcntB[0], popsB = 0;
    bool actA = headA < tailA, actB = headB < tailB;
    int iA = 1, iB = 1;
    float a0c = 0.f, a1c = 0.f, b0c = 0.f, b1c = 0.f;
    if (actA) { iA = queueA[0]; a0c = cstA[(iA - 1) * NN + lane]; a1c = cstA[(iA - 1) * NN + lane + 64]; }
    if (actB) { iB = queueB[0]; b0c = cstB[(iB - 1) * NN + lane]; b1c = cstB[(iB - 1) * NN + lane + 64]; }
    for (int g = 0; (actA || actB) && g < 6 * NN + 4; ++g) {
      const bool doA = actA, doB = actB;
      // stable-slot next-pop prefetch (appends only go to tail)
      const int inxA = (headA + 1 < tailA) ? queueA[headA + 1] : -1;
      const int inxB = (headB + 1 < tailB) ? queueB[headB + 1] : -1;
      // per-lane (min,max) pairs
      const double dA0 = (double)a0c - vA[0], dA1 = (double)a1c - vA[1];
      const double dB0 = (double)b0c - vB[0], dB1 = (double)b1c - vB[1];
      double dmnA, dmxA, dmnB, dmxB; int jmnA, jmnB;
      if (dA1 < dA0) { dmnA = dA1; dmxA = dA0; jmnA = lane + 64; } else { dmnA = dA0; dmxA = dA1; jmnA = lane; }
      if (dB1 < dB0) { dmnB = dB1; dmxB = dB0; jmnB = lane + 64; } else { dmnB = dB0; dmxB = dB1; jmnB = lane; }
      const unsigned kaA = __float_as_uint((float)dmnA), kbA = __float_as_uint((float)dmxA);
      const unsigned kaB = __float_as_uint((float)dmnB), kbB = __float_as_uint((float)dmxB);
      unsigned m1kA, m2kA, m1kB, m2kB;
      wave_min2_u32x2(kaA, kbA, kaB, kbB, m1kA, m2kA, m1kB, m2kB);
      const unsigned long long bmA = __ballot(kaA == m1kA);
      const unsigned long long bmB = __ballot(kaB == m1kB);
      const int winA = (int)__ffsll(bmA) - 1;
      const int winB = (int)__ffsll(bmB) - 1;
      const double m1A = readlane_f64(dmnA, winA);
      const double m1B = readlane_f64(dmnB, winB);
      const int j1A = __builtin_amdgcn_readlane(jmnA, winA);
      const int j1B = __builtin_amdgcn_readlane(jmnB, winB);
      const unsigned long long bA2 = __ballot(kaA == m2kA) & ~(1ull << winA);
      const unsigned long long bA3 = __ballot(kbA == m2kA);
      const unsigned long long bB2 = __ballot(kaB == m2kB) & ~(1ull << winB);
      const unsigned long long bB3 = __ballot(kbB == m2kB);
      const int lA1 = bA2 ? (int)__ffsll(bA2) - 1 : 64;
      const int lA2 = bA3 ? (int)__ffsll(bA3) - 1 : 64;
      const int lB1 = bB2 ? (int)__ffsll(bB2) - 1 : 64;
      const int lB2 = bB3 ? (int)__ffsll(bB3) - 1 : 64;
      double m2A = (lA1 <= lA2) ? readlane_f64(dmnA, lA1 < 64 ? lA1 : 63)
                                : readlane_f64(dmxA, lA2 < 64 ? lA2 : 63);
      double m2B = (lB1 <= lB2) ? readlane_f64(dmnB, lB1 < 64 ? lB1 : 63)
                                : readlane_f64(dmxB, lB2 < 64 ? lB2 : 63);
      m2A = fmax(m2A, m1A);
      m2B = fmax(m2B, m1B);
      const int ownA = j1A & 63, hkA = j1A >> 6;
      const int ownB = j1B & 63, hkB = j1B >> 6;
      const int kkA = __builtin_amdgcn_readlane(hkA ? pA[1] : pA[0], ownA);
      const int kkB = __builtin_amdgcn_readlane(hkB ? pB[1] : pB[0], ownB);
      const double oldpuA = readlane_f64(hkA ? puA[1] : puA[0], ownA);
      const double oldpuB = readlane_f64(hkB ? puB[1] : puB[0], ownB);
      // guarded state updates + next-row prefetch, batch A
      if (doA) {
        if (lane == ownA) {
          if (hkA) { vA[1] -= (m2A - m1A); pA[1] = iA; puA[1] = m2A; }
          else     { vA[0] -= (m2A - m1A); pA[0] = iA; puA[0] = m2A; }
        }
        if (lane == 0) {
          u_rowA[iA] = m2A;
          if (kkA != 0) { u_rowA[kkA] = oldpuA; queueA[tailA] = kkA; }
        }
        if (kkA != 0) ++tailA;
        ++headA; ++popsA;
        actA = (headA < tailA) && (popsA < 3 * NN);
        const int inext = (inxA >= 0) ? inxA : kkA;
        if (actA) {
          iA = inext;
          a0c = cstA[(iA - 1) * NN + lane]; a1c = cstA[(iA - 1) * NN + lane + 64];
        }
      }
      // guarded state updates + next-row prefetch, batch B
      if (doB) {
        if (lane == ownB) {
          if (hkB) { vB[1] -= (m2B - m1B); pB[1] = iB; puB[1] = m2B; }
          else     { vB[0] -= (m2B - m1B); pB[0] = iB; puB[0] = m2B; }
        }
        if (lane == 0) {
          u_rowB[iB] = m2B;
          if (kkB != 0) { u_rowB[kkB] = oldpuB; queueB[tailB] = kkB; }
        }
        if (kkB != 0) ++tailB;
        ++headB; ++popsB;
        actB = (headB < tailB) && (popsB < 3 * NN);
        const int inext = (inxB >= 0) ? inxB : kkB;
        if (actB) {
          iB = inext;
          b0c = cstB[(iB - 1) * NN + lane]; b1c = cstB[(iB - 1) * NN + lane + 64];
        }
      }
    }
  }
  __syncthreads();

  // ---- rebuild free-row masks after ARR (reuse colrow as flags) ----
  for (int t = lane; t < NN; t += 64) { colrowA[t] = 0; colrowB[t] = 0; }
  __syncthreads();
  if (pA[0] > 0) colrowA[pA[0] - 1] = 1;
  if (pA[1] > 0) colrowA[pA[1] - 1] = 1;
  if (pB[0] > 0) colrowB[pB[0] - 1] = 1;
  if (pB[1] > 0) colrowB[pB[1] - 1] = 1;
  __syncthreads();
  unsigned long long fmA0 = __ballot(colrowA[lane] == 0);
  unsigned long long fmA1 = __ballot(colrowA[lane + 64] == 0);
  unsigned long long fmB0 = __ballot(colrowB[lane] == 0);
  unsigned long long fmB1 = __ballot(colrowB[lane + 64] == 0);

  const unsigned INFBITS = 0x7f800000u;

  // ---- fused register Dijkstra over remaining free rows of both batches ----
  double DA0 = 0.0, DA1 = 0.0, DB0 = 0.0, DB1 = 0.0, u_iA = 0.0, u_iB = 0.0;
  int wayA0 = 0, wayA1 = 0, wayB0 = 0, wayB1 = 0;
  int usedA0 = 1, usedA1 = 1, usedB0 = 1, usedB1 = 1;
  int rowA = 0, rowB = 0;
  bool busyA = false, busyB = false;
  // next free row (uniform register masks)
  {
    if (fmA0)      { rowA = (int)__ffsll(fmA0); fmA0 &= fmA0 - 1; }
    else if (fmA1) { rowA = 64 + (int)__ffsll(fmA1); fmA1 &= fmA1 - 1; }
    busyA = rowA > 0;
    if (busyA) {
      u_iA = u_rowA[rowA];
      DA0 = (double)cstA[(rowA - 1) * NN + lane]      - u_iA - vA[0]; wayA0 = 0; usedA0 = 0;
      DA1 = (double)cstA[(rowA - 1) * NN + lane + 64] - u_iA - vA[1]; wayA1 = 0; usedA1 = 0;
    }
    if (fmB0)      { rowB = (int)__ffsll(fmB0); fmB0 &= fmB0 - 1; }
    else if (fmB1) { rowB = 64 + (int)__ffsll(fmB1); fmB1 &= fmB1 - 1; }
    busyB = rowB > 0;
    if (busyB) {
      u_iB = u_rowB[rowB];
      DB0 = (double)cstB[(rowB - 1) * NN + lane]      - u_iB - vB[0]; wayB0 = 0; usedB0 = 0;
      DB1 = (double)cstB[(rowB - 1) * NN + lane + 64] - u_iB - vB[1]; wayB1 = 0; usedB1 = 0;
    }
  }
  for (int g = 0; (busyA || busyB) && g < 40000; ++g) {
    // per-lane keys + relax-base candidates (both batches)
    const float prA0 = usedA0 ? __uint_as_float(INFBITS) : fmaxf((float)DA0, 0.0f);
    const float prA1 = usedA1 ? __uint_as_float(INFBITS) : fmaxf((float)DA1, 0.0f);
    const int k2lA = (prA1 < prA0) ? 1 : 0;
    const unsigned keyA = __float_as_uint(k2lA ? prA1 : prA0);
    const double DselA = k2lA ? DA1 : DA0;
    const double basecA = DselA - (k2lA ? puA[1] : puA[0]);
    const float prB0 = usedB0 ? __uint_as_float(INFBITS) : fmaxf((float)DB0, 0.0f);
    const float prB1 = usedB1 ? __uint_as_float(INFBITS) : fmaxf((float)DB1, 0.0f);
    const int k2lB = (prB1 < prB0) ? 1 : 0;
    const unsigned keyB = __float_as_uint(k2lB ? prB1 : prB0);
    const double DselB = k2lB ? DB1 : DB0;
    const double basecB = DselB - (k2lB ? puB[1] : puB[0]);
    // fused argmin
    unsigned rminA = keyA, rminB = keyB;
    wave_min_u32x2(rminA, rminB);
    const int winA = (int)__ffsll(__ballot(keyA == rminA)) - 1;
    const int winB = (int)__ffsll(__ballot(keyB == rminB)) - 1;
    // meta readlanes -> row indices -> issue LDS row loads ASAP
    const int metaA = __builtin_amdgcn_readlane(((k2lA ? pA[1] : pA[0]) << 1) | k2lA, winA);
    const int metaB = __builtin_amdgcn_readlane(((k2lB ? pB[1] : pB[0]) << 1) | k2lB, winB);
    const int i0A = metaA >> 1, k2wA = metaA & 1;
    const int i0B = metaB >> 1, k2wB = metaB & 1;
    const int bjA = 1 + winA + (k2wA << 6);
    const int bjB = 1 + winB + (k2wB << 6);
    const float c0A = cstA[((i0A - 1) & 127) * NN + lane];
    const float c1A = cstA[((i0A - 1) & 127) * NN + lane + 64];
    const float c0B = cstB[((i0B - 1) & 127) * NN + lane];
    const float c1B = cstB[((i0B - 1) & 127) * NN + lane + 64];
    const double baseA = readlane_f64(basecA, winA);
    const double baseB = readlane_f64(basecB, winB);
    const bool finA = busyA && (i0A == 0);
    const bool finB = busyB && (i0B == 0);
    // relax (non-finish iterations)
    if (busyA && !finA) {
      if (lane == winA) { if (k2wA) usedA1 = 1; else usedA0 = 1; }
      if (!usedA0) { const double cand = (double)c0A + baseA - vA[0]; if (cand < DA0) { DA0 = cand; wayA0 = bjA; } }
      if (!usedA1) { const double cand = (double)c1A + baseA - vA[1]; if (cand < DA1) { DA1 = cand; wayA1 = bjA; } }
    }
    if (busyB && !finB) {
      if (lane == winB) { if (k2wB) usedB1 = 1; else usedB0 = 1; }
      if (!usedB0) { const double cand = (double)c0B + baseB - vB[0]; if (cand < DB0) { DB0 = cand; wayB0 = bjB; } }
      if (!usedB1) { const double cand = (double)c1B + baseB - vB[1]; if (cand < DB1) { DB1 = cand; wayB1 = bjB; } }
    }
    // finish: duals + augment walk + next row (serial, rare)
    if (finA) {
      const double DfA = readlane_f64(DselA, winA);
      if (usedA0) { const double diff = DfA - DA0; vA[0] -= diff; puA[0] += diff; }
      if (usedA1) { const double diff = DfA - DA1; vA[1] -= diff; puA[1] += diff; }
      int j = bjA;
      for (int g2 = 0; g2 < NN + 2; ++g2) {
        const int own = (j - 1) & 63, hk = (j - 1) >> 6;
        const int wj = __builtin_amdgcn_readlane(hk ? wayA1 : wayA0, own);
        int pn; double pun;
        if (wj == 0) { pn = rowA; pun = u_iA + DfA; }
        else {
          const int o2 = (wj - 1) & 63, h2 = (wj - 1) >> 6;
          pn  = __builtin_amdgcn_readlane(h2 ? pA[1] : pA[0], o2);
          pun = readlane_f64(h2 ? puA[1] : puA[0], o2);
        }
        if (lane == own) { if (hk) { pA[1] = pn; puA[1] = pun; } else { pA[0] = pn; puA[0] = pun; } }
        if (wj == 0) break;
        j = wj;
      }
      rowA = 0;
      if (fmA0)      { rowA = (int)__ffsll(fmA0); fmA0 &= fmA0 - 1; }
      else if (fmA1) { rowA = 64 + (int)__ffsll(fmA1); fmA1 &= fmA1 - 1; }
      busyA = rowA > 0;
      if (busyA) {
        u_iA = u_rowA[rowA];
        DA0 = (double)cstA[(rowA - 1) * NN + lane]      - u_iA - vA[0]; wayA0 = 0; usedA0 = 0;
        DA1 = (double)cstA[(rowA - 1) * NN + lane + 64] - u_iA - vA[1]; wayA1 = 0; usedA1 = 0;
      }
    }
    if (finB) {
      const double DfB = readlane_f64(DselB, winB);
      if (usedB0) { const double diff = DfB - DB0; vB[0] -= diff; puB[0] += diff; }
      if (usedB1) { const double diff = DfB - DB1; vB[1] -= diff; puB[1] += diff; }
      int j = bjB;
      for (int g2 = 0; g2 < NN + 2; ++g2) {
        const int own = (j - 1) & 63, hk = (j - 1) >> 6;
        const int wj = __builtin_amdgcn_readlane(hk ? wayB1 : wayB0, own);
        int pn; double pun;
        if (wj == 0) { pn = rowB; pun = u_iB + DfB; }
        else {
          const int o2 = (wj - 1) & 63, h2 = (wj - 1) >> 6;
          pn  = __builtin_amdgcn_readlane(h2 ? pB[1] : pB[0], o2);
          pun = readlane_f64(h2 ? puB[1] : puB[0], o2);
        }
        if (lane == own) { if (hk) { pB[1] = pn; puB[1] = pun; } else { pB[0] = pn; puB[0] = pun; } }
        if (wj == 0) break;
        j = wj;
      }
      rowB = 0;
      if (fmB0)      { rowB = (int)__ffsll(fmB0); fmB0 &= fmB0 - 1; }
      else if (fmB1) { rowB = 64 + (int)__ffsll(fmB1); fmB1 &= fmB1 - 1; }
      busyB = rowB > 0;
      if (busyB) {
        u_iB = u_rowB[rowB];
        DB0 = (double)cstB[(rowB - 1) * NN + lane]      - u_iB - vB[0]; wayB0 = 0; usedB0 = 0;
        DB1 = (double)cstB[(rowB - 1) * NN + lane + 64] - u_iB - vB[1]; wayB1 = 0; usedB1 = 0;
      }
    }
  }

  // ---- write results: cols[b][p[j]-1] = j ----
  { const int r = pA[0] - 1; if (r >= 0 && r < NN) cols[bA * NN + r] = lane; }
  { const int r = pA[1] - 1; if (r >= 0 && r < NN) cols[bA * NN + r] = lane + 64; }
  { const int r = pB[0] - 1; if (r >= 0 && r < NN) cols[bB * NN + r] = lane; }
  { const int r = pB[1] - 1; if (r >= 0 && r < NN) cols[bB * NN + r] = lane + 64; }
}

// ---------------------------------------------------------------------------
// Kernel C: gather outputs / probs by cols, write cols as float. (unchanged)
// ---------------------------------------------------------------------------
__global__ __launch_bounds__(256) void gather_kernel(const float* __restrict__ outs,
                                                     const float* __restrict__ probs,
                                                     const int* __restrict__ cols,
                                                     float* __restrict__ out) {
  const int bi = blockIdx.x;            // 0..8191
  const int b  = bi >> 7;
  const int col = cols[bi] & (NN - 1);  // clamp: garbage -> wrong answer, not fault
  const float4* src = (const float4*)(outs + ((size_t)(b * NN + col)) * ND);
  float4* dst = (float4*)(out + (size_t)bi * ND);
  const int t = threadIdx.x;
  dst[t]       = src[t];
  dst[t + 256] = src[t + 256];
  if (t == 0) {
    const size_t PROB_OFF = (size_t)NB * NN * ND;            // 16777216
    out[PROB_OFF + bi]        = probs[b * NN + col];
    out[PROB_OFF + 8192 + bi] = (float)(cols[bi] & (NN - 1));
  }
}

extern "C" void kernel_launch(void* const* d_in, const int* in_sizes, int n_in,
                              void* d_out, int out_size, void* d_ws, size_t ws_size,
                              hipStream_t stream) {
  const float* X = (const float*)d_in[0];   // inputs            [64,128,2048] f32
  const float* Y = (const float*)d_in[1];   // stacked_outputs   [64,128,2048] f32
  const float* P = (const float*)d_in[2];   // member_probs      [64,128,1]    f32
  float* out = (float*)d_out;

  float* cost = (float*)d_ws;                                   // 4 MB
  int* cols = (int*)((char*)d_ws + (size_t)NB * NN * NN * 4);   // 32 KB

  cost_kernel<<<dim3(NB * 4), dim3(256), 0, stream>>>(X, Y, cost);
  hungarian_kernel<<<dim3(NB / 2), dim3(64), 0, stream>>>(cost, cols);
  gather_kernel<<<dim3(NB * NN), dim3(256), 0, stream>>>(Y, P, cols, out);
}

// Round 12
// 706.896 us; speedup vs baseline: 1.4868x; 1.4868x over previous
//
#include <hip/hip_runtime.h>

#define NB 64
#define NN 128
#define ND 2048

// ---------------------------------------------------------------------------
// Kernel A: cost[b][i][j] = sqrt(max(||x_i||^2 + ||y_j||^2 - 2 x_i.y_j, 0))
// 64x64 tiles, 8 rows x 2 cols per thread: per kk = 2x ds_read_b128 (X, wave-
// broadcast) + 2x conflict-free b32 (Y) + 26 VALU -> ~1.8x VALU efficiency
// vs the 4x4 version, grid still 256 blocks x 4 waves (full CU coverage).
// ---------------------------------------------------------------------------
__global__ __launch_bounds__(256) void cost_kernel(const float* __restrict__ X,
                                                   const float* __restrict__ Y,
                                                   float* __restrict__ cost) {
  const int b  = blockIdx.x >> 2;
  const int rt = (blockIdx.x >> 1) & 1;
  const int ct = blockIdx.x & 1;
  const int rbase = rt * 64;
  const int cbase = ct * 64;
  __shared__ float Xs[32][72];    // [k][row], 64 rows + 8 pad (rows 16B-aligned)
  __shared__ float Ys[32][65];    // [k][col], 64 cols + 1 pad (b32 conflict-free)
  __shared__ float xsq_s[64];
  __shared__ float ysq_s[64];
  const int tid = threadIdx.x;
  const int tr = tid >> 5;        // 0..7  -> rows 8tr..8tr+7
  const int tc = tid & 31;        // 0..31 -> cols tc, tc+32
  float acc[8][2] = {};
  float xsq[8] = {};
  float ysq[2] = {};
  const float* Xb = X + ((size_t)(b * NN + rbase)) * ND;
  const float* Yb = Y + ((size_t)(b * NN + cbase)) * ND;

  for (int kb = 0; kb < ND; kb += 32) {
    __syncthreads();
    // stage X tile: 64 rows x 32 k = 512 float4, 2 per thread
#pragma unroll
    for (int l = 0; l < 2; ++l) {
      const int idx = tid + 256 * l;       // 0..511
      const int row = idx >> 3;            // 0..63
      const int kk4 = (idx & 7) << 2;      // 0,4,..,28
      float4 v = *(const float4*)(Xb + (size_t)row * ND + kb + kk4);
      Xs[kk4 + 0][row] = v.x; Xs[kk4 + 1][row] = v.y;
      Xs[kk4 + 2][row] = v.z; Xs[kk4 + 3][row] = v.w;
    }
    // stage Y tile: 64 cols x 32 k = 512 float4, 2 per thread
#pragma unroll
    for (int l = 0; l < 2; ++l) {
      const int idx = tid + 256 * l;
      const int col = idx >> 3;
      const int kk4 = (idx & 7) << 2;
      float4 v = *(const float4*)(Yb + (size_t)col * ND + kb + kk4);
      Ys[kk4 + 0][col] = v.x; Ys[kk4 + 1][col] = v.y;
      Ys[kk4 + 2][col] = v.z; Ys[kk4 + 3][col] = v.w;
    }
    __syncthreads();
#pragma unroll 4
    for (int kk = 0; kk < 32; ++kk) {
      const float4 xa = *(const float4*)&Xs[kk][8 * tr];
      const float4 xb = *(const float4*)&Xs[kk][8 * tr + 4];
      const float xv[8] = {xa.x, xa.y, xa.z, xa.w, xb.x, xb.y, xb.z, xb.w};
      const float yv[2] = {Ys[kk][tc], Ys[kk][tc + 32]};
#pragma unroll
      for (int ii = 0; ii < 8; ++ii) xsq[ii] += xv[ii] * xv[ii];
#pragma unroll
      for (int jj = 0; jj < 2; ++jj) ysq[jj] += yv[jj] * yv[jj];
#pragma unroll
      for (int ii = 0; ii < 8; ++ii)
#pragma unroll
        for (int jj = 0; jj < 2; ++jj)
          acc[ii][jj] += xv[ii] * yv[jj];
    }
  }
  if (tc == 0) {
#pragma unroll
    for (int ii = 0; ii < 8; ++ii) xsq_s[8 * tr + ii] = xsq[ii];
  }
  if (tr == 0) {
#pragma unroll
    for (int jj = 0; jj < 2; ++jj) ysq_s[tc + 32 * jj] = ysq[jj];
  }
  __syncthreads();
#pragma unroll
  for (int ii = 0; ii < 8; ++ii) {
    const int r = rbase + 8 * tr + ii;
    const float xs = xsq_s[8 * tr + ii];
#pragma unroll
    for (int jj = 0; jj < 2; ++jj) {
      const int c = cbase + tc + 32 * jj;
      const float d2 = xs + ysq_s[tc + 32 * jj] - 2.0f * acc[ii][jj];
      cost[((size_t)(b * NN + r)) * NN + c] = sqrtf(fmaxf(d2, 0.0f));
    }
  }
}

// ---------------------------------------------------------------------------
// Cross-lane helpers (DPP-only; no ds_bpermute anywhere).
// ---------------------------------------------------------------------------
__device__ __forceinline__ unsigned umin2(unsigned a, unsigned b) { return a < b ? a : b; }
__device__ __forceinline__ unsigned umax2(unsigned a, unsigned b) { return a > b ? a : b; }

__device__ __forceinline__ unsigned wave_min_u32(unsigned x) {
  unsigned t;
  t = (unsigned)__builtin_amdgcn_update_dpp((int)x, (int)x, 0x111, 0xF, 0xF, false); x = umin2(x, t); // row_shr:1
  t = (unsigned)__builtin_amdgcn_update_dpp((int)x, (int)x, 0x112, 0xF, 0xF, false); x = umin2(x, t); // row_shr:2
  t = (unsigned)__builtin_amdgcn_update_dpp((int)x, (int)x, 0x114, 0xF, 0xF, false); x = umin2(x, t); // row_shr:4
  t = (unsigned)__builtin_amdgcn_update_dpp((int)x, (int)x, 0x118, 0xF, 0xF, false); x = umin2(x, t); // row_shr:8
  t = (unsigned)__builtin_amdgcn_update_dpp((int)x, (int)x, 0x142, 0xA, 0xF, false); x = umin2(x, t); // row_bcast:15
  t = (unsigned)__builtin_amdgcn_update_dpp((int)x, (int)x, 0x143, 0xC, 0xF, false); x = umin2(x, t); // row_bcast:31
  return (unsigned)__builtin_amdgcn_readlane((int)x, 63);
}

// dual (min, 2nd-min) reduction step; DPP ctrl/row_mask as template constants
// (the builtin requires integer-constant operands at the AST level).
// Requires a <= b per lane on entry. Valid for the non-idempotent 2nd-min
// combine because the lane-63 path merges pairwise-disjoint windows:
// [48,63] + [32,47] (bcast15) + [0,31] (bcast31).
template <int CTRL, int RMASK>
__device__ __forceinline__ void min2_step(unsigned& a, unsigned& b) {
  unsigned ap = (unsigned)__builtin_amdgcn_update_dpp((int)a, (int)a, CTRL, RMASK, 0xF, false);
  unsigned bp = (unsigned)__builtin_amdgcn_update_dpp((int)b, (int)b, CTRL, RMASK, 0xF, false);
  unsigned hi = umax2(a, ap);
  a = umin2(a, ap);
  b = umin2(umin2(b, bp), hi);
}

__device__ __forceinline__ void wave_min2_u32(unsigned a, unsigned b,
                                              unsigned& m1k, unsigned& m2k) {
  min2_step<0x111, 0xF>(a, b);   // row_shr:1
  min2_step<0x112, 0xF>(a, b);   // row_shr:2
  min2_step<0x114, 0xF>(a, b);   // row_shr:4
  min2_step<0x118, 0xF>(a, b);   // row_shr:8
  min2_step<0x142, 0xA>(a, b);   // row_bcast:15
  min2_step<0x143, 0xC>(a, b);   // row_bcast:31
  m1k = (unsigned)__builtin_amdgcn_readlane((int)a, 63);
  m2k = (unsigned)__builtin_amdgcn_readlane((int)b, 63);
}

__device__ __forceinline__ double readlane_f64(double d, int lane) {
  int lo = __builtin_amdgcn_readlane(__double2loint(d), lane);
  int hi = __builtin_amdgcn_readlane(__double2hiint(d), lane);
  return __hiloint2double(hi, lo);
}

// ---------------------------------------------------------------------------
// Kernel B: JV / Hungarian — byte-identical revert to the validated 533 us
// version (round-9 bench). Full JV init (column reduction + greedy claim +
// reduction transfer + ARR) then register-resident wave-synchronous Dijkstra.
// One wave per batch; lane owns cols {lane, lane+64}. Exact f64 state; f32
// monotone-bit keys for argmin. All loops hard-capped; control flow uniform.
// ---------------------------------------------------------------------------
__global__ __launch_bounds__(64) void hungarian_kernel(const float* __restrict__ cost,
                                                       int* __restrict__ cols) {
  const int b = blockIdx.x;
  const int lane = threadIdx.x;
  __shared__ float cst[NN * NN];     // 64 KB
  __shared__ int colrow[NN];         // init: argmin row per col; later: row-matched flags
  __shared__ int rwin[NN];           // init: winning col per row (or -1)
  __shared__ double u_row[NN + 1];   // u for rows (free/dispossessed roots)
  __shared__ int queue[4 * NN + 8];  // ARR work queue (1-based rows)
  __shared__ int qcnt[1];

  // load cost matrix into LDS (float4 coalesced)
  {
    const float4* src = (const float4*)(cost + (size_t)b * NN * NN);
    float4* dst = (float4*)cst;
    for (int t = lane; t < NN * NN / 4; t += 64) dst[t] = src[t];
  }
  for (int t = lane; t <= NN; t += 64) u_row[t] = 0.0;
  __syncthreads();

  // ---- column reduction: v[j] = min_i c[i][j], argmin row per col ----
  float cmin[2]; int cargr[2];
#pragma unroll
  for (int k2 = 0; k2 < 2; ++k2) {
    const int j = lane + 64 * k2;
    float mn = cst[j]; int ar = 0;
    for (int r = 1; r < NN; ++r) {
      float cr = cst[r * NN + j];
      if (cr < mn) { mn = cr; ar = r; }
    }
    cmin[k2] = mn; cargr[k2] = ar;
    colrow[j] = ar;
  }
  __syncthreads();
  // deterministic claim: row r matched to the SMALLEST col j with colrow[j]==r
  int rowwin[2] = {-1, -1};
  for (int j = 0; j < NN; ++j) {
    int rr = colrow[j];   // uniform broadcast read
#pragma unroll
    for (int k2 = 0; k2 < 2; ++k2) {
      if (rr == lane + 64 * k2 && rowwin[k2] < 0) rowwin[k2] = j;
    }
  }
#pragma unroll
  for (int k2 = 0; k2 < 2; ++k2) rwin[lane + 64 * k2] = rowwin[k2];
  const unsigned long long mask0 = __ballot(rowwin[0] >= 0);  // rows 0..63 matched
  const unsigned long long mask1 = __ballot(rowwin[1] >= 0);  // rows 64..127 matched
  __syncthreads();

  // per-column state (registers)
  int    p_[2];
  double pu_[2], v_[2];
#pragma unroll
  for (int k2 = 0; k2 < 2; ++k2) {
    const int j = lane + 64 * k2;
    const int r = cargr[k2];
    p_[k2]  = (rwin[r] == j) ? (r + 1) : 0;
    pu_[k2] = 0.0;
    v_[k2]  = (double)cmin[k2];
  }

  // ---- reduction transfer: for each greedy-matched row i with col j1:
  //      mu = min_{j != j1}(c - v); v[j1] -= mu; u_i (=pu at j1) = mu.
  for (int i = 1; i <= NN; ++i) {
    const bool matched = (i - 1) < 64 ? ((mask0 >> (i - 1)) & 1ull)
                                      : ((mask1 >> (i - 65)) & 1ull);
    if (!matched) continue;
    const int j1 = rwin[i - 1];          // uniform LDS read
    const float* crow = &cst[(i - 1) * NN];
    double d0 = (double)crow[lane]      - v_[0];
    double d1 = (double)crow[lane + 64] - v_[1];
    if (lane == (j1 & 63)) { if (j1 >> 6) d1 = 1e300; else d0 = 1e300; }
    const double dmn = fmin(d0, d1);
    const unsigned k = __float_as_uint((float)dmn);  // 1e300 -> +inf bits, still monotone
    const unsigned mk = wave_min_u32(k);
    const unsigned long long bm = __ballot(k == mk);
    const int wl = (int)__ffsll(bm) - 1;
    const double mu = readlane_f64(dmn, wl);
    if (lane == (j1 & 63)) {
      if (j1 >> 6) { v_[1] -= mu; pu_[1] = mu; }
      else         { v_[0] -= mu; pu_[0] = mu; }
    }
  }

  // ---- augmenting row reduction (ARR), DPP dual-min version ----
  if (lane == 0) {
    int t = 0;
    for (int r = 1; r <= NN; ++r) {
      const bool m = (r - 1) < 64 ? ((mask0 >> (r - 1)) & 1ull)
                                  : ((mask1 >> (r - 65)) & 1ull);
      if (!m) queue[t++] = r;
    }
    qcnt[0] = t;
  }
  __syncthreads();
  {
    int head = 0, tail = qcnt[0];
    for (int pops = 0; head < tail && pops < 3 * NN; ++pops) {
      const int i = queue[head++];           // uniform broadcast read
      const float* crow = cst + (i - 1) * NN;
      const double d0 = (double)crow[lane]      - v_[0];
      const double d1 = (double)crow[lane + 64] - v_[1];
      double dmn, dmx; int jmn;
      if (d1 < d0) { dmn = d1; dmx = d0; jmn = lane + 64; }
      else         { dmn = d0; dmx = d1; jmn = lane; }
      const unsigned ka = __float_as_uint((float)dmn);
      const unsigned kb = __float_as_uint((float)dmx);
      unsigned m1k, m2k;
      wave_min2_u32(ka, kb, m1k, m2k);
      const unsigned long long bA = __ballot(ka == m1k);
      const int win = (int)__ffsll(bA) - 1;
      const double m1 = readlane_f64(dmn, win);
      const int j1 = __builtin_amdgcn_readlane(jmn, win);
      const unsigned long long bA2 = __ballot(ka == m2k) & ~(1ull << win);
      const unsigned long long bB2 = __ballot(kb == m2k);
      const int lA = bA2 ? (int)__ffsll(bA2) - 1 : 64;
      const int lB = bB2 ? (int)__ffsll(bB2) - 1 : 64;
      double m2 = (lA <= lB) ? readlane_f64(dmn, lA < 64 ? lA : 63)
                             : readlane_f64(dmx, lB < 64 ? lB : 63);
      m2 = fmax(m2, m1);
      // assign i -> j1; v[j1] -= (m2 - m1); u[i] = m2; dispossess k (if any)
      const int own = j1 & 63, hk = j1 >> 6;
      const int    psel  = hk ? p_[1]  : p_[0];
      const double pusel = hk ? pu_[1] : pu_[0];
      const int kk = __builtin_amdgcn_readlane(psel, own);
      const double oldpu = readlane_f64(pusel, own);
      if (lane == own) {
        if (hk) { v_[1] -= (m2 - m1); p_[1] = i; pu_[1] = m2; }
        else    { v_[0] -= (m2 - m1); p_[0] = i; pu_[0] = m2; }
      }
      if (lane == 0) {
        u_row[i] = m2;
        if (kk != 0) { u_row[kk] = oldpu; queue[tail] = kk; }
      }
      if (kk != 0) ++tail;
      __syncthreads();   // queue / u_row visibility for next pop
    }
  }
  __syncthreads();

  // ---- rebuild free-row masks after ARR (reuse colrow as flags) ----
  for (int t = lane; t < NN; t += 64) colrow[t] = 0;
  __syncthreads();
  if (p_[0] > 0) colrow[p_[0] - 1] = 1;
  if (p_[1] > 0) colrow[p_[1] - 1] = 1;
  __syncthreads();
  const unsigned long long fmask0 = __ballot(colrow[lane] == 0);       // free rows 1..64
  const unsigned long long fmask1 = __ballot(colrow[lane + 64] == 0);  // free rows 65..128

  const unsigned INFBITS = 0x7f800000u;  // +inf f32 bits

  // ---- augment each remaining free row with register Dijkstra ----
  for (int i = 1; i <= NN; ++i) {
    const bool freerow = (i - 1) < 64 ? ((fmask0 >> (i - 1)) & 1ull)
                                      : ((fmask1 >> (i - 65)) & 1ull);
    if (!freerow) continue;

    const double u_i = u_row[i];   // uniform broadcast read
    double D_[2]; int way_[2]; int used_[2] = {0, 0};
    {
      const float* crow = &cst[(i - 1) * NN];
      D_[0] = (double)crow[lane]      - u_i - v_[0];  way_[0] = 0;
      D_[1] = (double)crow[lane + 64] - u_i - v_[1];  way_[1] = 0;
    }
    double Dfinal = 0.0; int jF = 1;
    for (int it = 0; it < NN + 2; ++it) {        // provable bound: <= NN+1
      // per-lane best of its 2 columns (exact f32 key, D>=0 clamped)
      const float pr0 = used_[0] ? __uint_as_float(INFBITS) : fmaxf((float)D_[0], 0.0f);
      const float pr1 = used_[1] ? __uint_as_float(INFBITS) : fmaxf((float)D_[1], 0.0f);
      const int   k2l = (pr1 < pr0) ? 1 : 0;
      const unsigned key = __float_as_uint(k2l ? pr1 : pr0);
      // wave argmin via DPP min + ballot + ffs (lowest lane on ties)
      const unsigned rmin = wave_min_u32(key);
      const unsigned long long wm = __ballot(key == rmin);
      const int winlane = (int)__ffsll(wm) - 1;
      // one meta readlane gives (i0, k2w) -> LDS row loads issue ASAP
      const int metal = ((k2l ? p_[1] : p_[0]) << 1) | k2l;
      const int meta = __builtin_amdgcn_readlane(metal, winlane);
      const int i0 = meta >> 1;
      const int k2w = meta & 1;
      const int bj = 1 + winlane + (k2w << 6);   // 1-based col
      const float* crow = &cst[((i0 - 1) & 127) * NN];
      const float c0 = crow[lane];          // in flight...
      const float c1 = crow[lane + 64];
      // ...overlapped with the exact-f64 readlanes
      const double bv = readlane_f64(k2l ? D_[1] : D_[0], winlane);
      if (i0 == 0) { Dfinal = bv; jF = bj; break; }   // free column reached
      const double u0 = readlane_f64(k2l ? pu_[1] : pu_[0], winlane);
      // mark used (static index) BEFORE relax so winner column is skipped
      if (lane == winlane) { if (k2w) used_[1] = 1; else used_[0] = 1; }
      const double base = bv - u0;
      if (!used_[0]) {
        const double cand = (double)c0 + base - v_[0];
        if (cand < D_[0]) { D_[0] = cand; way_[0] = bj; }
      }
      if (!used_[1]) {
        const double cand = (double)c1 + base - v_[1];
        if (cand < D_[1]) { D_[1] = cand; way_[1] = bj; }
      }
    }
    // potential updates (pre-augment matching semantics)
#pragma unroll
    for (int k2 = 0; k2 < 2; ++k2) {
      if (used_[k2]) {
        const double diff = Dfinal - D_[k2];
        v_[k2]  -= diff;
        pu_[k2] += diff;
      }
    }
    // augment along way (serial walk via readlanes; bounded; j uniform)
    int j = jF;
    for (int g = 0; g < NN + 2; ++g) {
      const int own = (j - 1) & 63;
      const int hk  = (j - 1) >> 6;
      const int wsel = hk ? way_[1] : way_[0];
      const int wj = __builtin_amdgcn_readlane(wsel, own);
      int pn; double pun;
      if (wj == 0) { pn = i; pun = u_i + Dfinal; }   // root row's new u
      else {
        const int o2 = (wj - 1) & 63, h2 = (wj - 1) >> 6;
        const int    psel2  = h2 ? p_[1]  : p_[0];
        const double pusel2 = h2 ? pu_[1] : pu_[0];
        pn  = __builtin_amdgcn_readlane(psel2, o2);
        pun = readlane_f64(pusel2, o2);
      }
      if (lane == own) {
        if (hk) { p_[1] = pn; pu_[1] = pun; }
        else    { p_[0] = pn; pu_[0] = pun; }
      }
      if (wj == 0) break;
      j = wj;
    }
  }

  // cols[b][p[j]-1] = j (0-based col)
#pragma unroll
  for (int k2 = 0; k2 < 2; ++k2) {
    const int r = p_[k2] - 1;
    if (r >= 0 && r < NN) cols[b * NN + r] = lane + 64 * k2;
  }
}

// ---------------------------------------------------------------------------
// Kernel C: gather outputs / probs by cols, write cols as float. (unchanged)
// ---------------------------------------------------------------------------
__global__ __launch_bounds__(256) void gather_kernel(const float* __restrict__ outs,
                                                     const float* __restrict__ probs,
                                                     const int* __restrict__ cols,
                                                     float* __restrict__ out) {
  const int bi = blockIdx.x;            // 0..8191
  const int b  = bi >> 7;
  const int col = cols[bi] & (NN - 1);  // clamp: garbage -> wrong answer, not fault
  const float4* src = (const float4*)(outs + ((size_t)(b * NN + col)) * ND);
  float4* dst = (float4*)(out + (size_t)bi * ND);
  const int t = threadIdx.x;
  dst[t]       = src[t];
  dst[t + 256] = src[t + 256];
  if (t == 0) {
    const size_t PROB_OFF = (size_t)NB * NN * ND;            // 16777216
    out[PROB_OFF + bi]        = probs[b * NN + col];
    out[PROB_OFF + 8192 + bi] = (float)(cols[bi] & (NN - 1));
  }
}

extern "C" void kernel_launch(void* const* d_in, const int* in_sizes, int n_in,
                              void* d_out, int out_size, void* d_ws, size_t ws_size,
                              hipStream_t stream) {
  const float* X = (const float*)d_in[0];   // inputs            [64,128,2048] f32
  const float* Y = (const float*)d_in[1];   // stacked_outputs   [64,128,2048] f32
  const float* P = (const float*)d_in[2];   // member_probs      [64,128,1]    f32
  float* out = (float*)d_out;

  float* cost = (float*)d_ws;                                   // 4 MB
  int* cols = (int*)((char*)d_ws + (size_t)NB * NN * NN * 4);   // 32 KB

  cost_kernel<<<dim3(NB * 4), dim3(256), 0, stream>>>(X, Y, cost);
  hungarian_kernel<<<dim3(NB), dim3(64), 0, stream>>>(cost, cols);
  gather_kernel<<<dim3(NB * NN), dim3(256), 0, stream>>>(Y, P, cols, out);
}